// Round 2
// baseline (1146.105 us; speedup 1.0000x reference)
//
#include <hip/hip_runtime.h>
#include <hip/hip_bf16.h>

// HGT forward, MI355X. Round 9b: transposed-MFMA epilogues (wide stores).
// R8 profile: gemm_qkv5 182us x2, MfmaUtil 3.5%, VALU 4.2%, HBM 11%, occ 19%
//  -> latency-bound on 160x 2B scattered stores/thread (channel-on-lane C/D
//     layout forces elementwise stores; KV interleave scatters them further).
// Fix: swap mfma operands (mfma(b,a)) so lane15 = node row, reg = 4 consecutive
// channels. Q becomes 8B stores; KV interleave {K0,K1,V0,V1,K2,K3,V2,V3}
// packs into ONE 16B short8 store per jc (slots 2*c0..2*c0+7). Per store instr
// the wave writes 16 full 64B lines. qkv5: 160->24 stores/thread; qkv3: 96->16;
// gemm_2t: 64->16 (+8B oldx loads). Loads/layouts/agg unchanged.
// (R9 fix: HIP predefines short4 -> renamed vector type to s4v.)

typedef __hip_bfloat16 bf16;
typedef __attribute__((ext_vector_type(8))) short short8;
typedef __attribute__((ext_vector_type(4))) short s4v;
typedef __attribute__((ext_vector_type(4))) float floatx4;

#define N_STMT 100000
#define N_FUNC 50000
#define N_TOT  150000
#define EDGES  200000
#define CCH 128
#define NBS1 782   // (N_STMT+127)/128
#define NBF1 391   // (N_FUNC+127)/128

__device__ __forceinline__ float b2f(bf16 x){ return __bfloat162float(x); }
__device__ __forceinline__ float bs2f(short s){
  union { short s; bf16 h; } u; u.s = s; return __bfloat162float(u.h);
}
__device__ __forceinline__ short f2bs(float x){
  union { bf16 h; short s; } u; u.h = __float2bfloat16(x); return u.s;
}
__device__ __forceinline__ float gelu_f(float x){
  return 0.5f * x * (1.f + tanhf(0.7978845608028654f * (x + 0.044715f * x * x * x)));
}

// ---------------- emb fp32 -> bf16 table ------------------------------------
__global__ __launch_bounds__(256) void emb2bf(
    const float* __restrict__ emb, bf16* __restrict__ ebf)
{
  long i = ((long)blockIdx.x * 256 + threadIdx.x) * 8;
  float4 f0 = *(const float4*)(emb + i);
  float4 f1 = *(const float4*)(emb + i + 4);
  short8 o;
  o[0]=f2bs(f0.x); o[1]=f2bs(f0.y); o[2]=f2bs(f0.z); o[3]=f2bs(f0.w);
  o[4]=f2bs(f1.x); o[5]=f2bs(f1.y); o[6]=f2bs(f1.z); o[7]=f2bs(f1.w);
  *(short8*)(ebf + i) = o;
}

// ---------------- pooled embedding: one wave per node -----------------------
__global__ __launch_bounds__(256) void pool_embed(
    const int* __restrict__ tok_s, const int* __restrict__ tok_f,
    const bf16* __restrict__ ebf, bf16* __restrict__ E_out)
{
  int n = blockIdx.x * 4 + (threadIdx.x >> 6);
  int lane = threadIdx.x & 63, g = lane >> 4, c16 = lane & 15;
  const int* tok = (n < N_STMT) ? (tok_s + n * 16) : (tok_f + (n - N_STMT) * 16);
  float acc[8] = {0.f,0.f,0.f,0.f,0.f,0.f,0.f,0.f};
#pragma unroll
  for (int j = 0; j < 4; j++) {
    int v = tok[g * 4 + j];
    short8 row = *(const short8*)(ebf + (long)v * CCH + c16 * 8);
#pragma unroll
    for (int q = 0; q < 8; q++) acc[q] += bs2f(row[q]);
  }
#pragma unroll
  for (int q = 0; q < 8; q++) {
    acc[q] += __shfl_xor(acc[q], 16);
    acc[q] += __shfl_xor(acc[q], 32);
  }
  if (g == 0) {
    short8 o;
#pragma unroll
    for (int q = 0; q < 8; q++) o[q] = f2bs(fmaxf(acc[q] * (1.f/16.f), 0.f));
    *(short8*)(E_out + (long)n * CCH + c16 * 8) = o;
  }
}

// ---------------- transpose+cast 10 raw weight matrices ---------------------
__global__ __launch_bounds__(256) void transp_w(
    const float* __restrict__ lin_w, const float* __restrict__ qw,
    const float* __restrict__ aw, bf16* __restrict__ out)
{
  int mat = blockIdx.y;
  const float* src = (mat < 2) ? lin_w + mat * 16384
                   : (mat < 6) ? qw + (mat - 2) * 16384
                               : aw + (mat - 6) * 16384;
  bf16* dst = out + mat * 16384;
  int idx = blockIdx.x * 256 + threadIdx.x;       // n*128+k
  int n = idx >> 7, k = idx & 127;
  dst[idx] = __float2bfloat16(src[k * 128 + n]);
}

// -------- ALL fused relation weights in one dispatch ------------------------
__global__ __launch_bounds__(256) void make_wr_all(
    const float* __restrict__ kw, const float* __restrict__ kb,
    const float* __restrict__ vw, const float* __restrict__ vb,
    const float* __restrict__ a_rel, const float* __restrict__ m_rel,
    bf16* __restrict__ WRT, float* __restrict__ Bf)
{
  int y = blockIdx.y;
  bool isV = y >= 6;
  int z = isV ? y - 6 : y;
  int l = z / 3, r = z % 3, st = (r == 2) ? 1 : 0;
  const float* W   = (isV ? vw : kw) + (l * 2 + st) * 16384;
  const float* b   = (isV ? vb : kb) + (l * 2 + st) * 128;
  const float* rel = (isV ? m_rel : a_rel) + z * 2048;
  bf16* Wrt = WRT + y * 16384;
  float* br = Bf + y * 128;

  int idx = blockIdx.x * 256 + threadIdx.x;
  if (idx < 128 * 128) {
    int c = idx >> 7, o = idx & 127;
    int h = o >> 4, e = o & 15;
    float acc = 0.f;
#pragma unroll
    for (int d = 0; d < 16; d++)
      acc += W[c * 128 + h * 16 + d] * rel[h * 256 + d * 16 + e];
    Wrt[o * 128 + c] = __float2bfloat16(acc);
  }
  if (idx < 128) {
    int h = idx >> 4, e = idx & 15;
    float acc = 0.f;
#pragma unroll
    for (int d = 0; d < 16; d++)
      acc += b[h * 16 + d] * rel[h * 256 + d * 16 + e];
    br[idx] = acc;
  }
}

// ---------------- fused 2-type MFMA GEMM (lin / out-proj) -------------------
// Grid = NBS1 + NBF1 blocks; block < NBS1 -> stmt rows, else func rows.
// Transposed MFMA: lane15 = node row, (quad*4+reg) = channel -> wide stores.
template <bool GELU_IN, bool RELU, bool BLEND, bool OUT_BF16>
__global__ __launch_bounds__(256) void gemm_2t(
    const bf16* __restrict__ Ab, const bf16* __restrict__ Wt0,
    const bf16* __restrict__ Wt1, const float* __restrict__ bias0,
    const float* __restrict__ bias1, const bf16* __restrict__ oldx,
    void* __restrict__ dstv, const float* __restrict__ skip2)
{
  const int wave = threadIdx.x >> 6, lane = threadIdx.x & 63;
  const int lane15 = lane & 15, quad = lane >> 4;
  const int bid = blockIdx.x;
  const int type = (bid >= NBS1);
  const long base = type ? (long)N_STMT * CCH : 0;
  const int Nrows = type ? N_FUNC : N_STMT;
  const long row0 = (long)(type ? bid - NBS1 : bid) * 128 + wave * 32;
  const bf16* Wt = type ? Wt1 : Wt0;
  const float* bias = type ? bias1 : bias0;

  floatx4 acc[2][8];
#pragma unroll
  for (int i = 0; i < 2; i++)
#pragma unroll
    for (int jc = 0; jc < 8; jc++) acc[i][jc] = (floatx4)(0.f);

#pragma unroll
  for (int kq = 0; kq < 4; kq++) {
    const int k0 = kq * 32 + quad * 8;
    short8 a[2];
#pragma unroll
    for (int i = 0; i < 2; i++) {
      long r = row0 + i * 16 + lane15;
      if (r >= Nrows) r = Nrows - 1;
      short8 t = *(const short8*)(Ab + base + r * CCH + k0);
      if constexpr (GELU_IN) {
#pragma unroll
        for (int q = 0; q < 8; q++) t[q] = f2bs(gelu_f(bs2f(t[q])));
      }
      a[i] = t;
    }
    short8 b[8];
#pragma unroll
    for (int jc = 0; jc < 8; jc++)
      b[jc] = *(const short8*)(Wt + (jc * 16 + lane15) * CCH + k0);
#pragma unroll
    for (int i = 0; i < 2; i++)
#pragma unroll
      for (int jc = 0; jc < 8; jc++)
        acc[i][jc] = __builtin_amdgcn_mfma_f32_16x16x32_bf16(
            b[jc], a[i], acc[i][jc], 0, 0, 0);
  }

  float g = 1.f, gi = 0.f;
  if (BLEND) {
    float sk = skip2[type];
    g = 1.f / (1.f + expf(-sk));
    gi = 1.f - g;
  }
#pragma unroll
  for (int i = 0; i < 2; i++) {
    long r = row0 + i * 16 + lane15;
    if (r < Nrows) {
#pragma unroll
      for (int jc = 0; jc < 8; jc++) {
        int c0 = jc * 16 + quad * 4;
        float4 bb = *(const float4*)(bias + c0);
        float v[4];
        v[0] = acc[i][jc][0] + bb.x;
        v[1] = acc[i][jc][1] + bb.y;
        v[2] = acc[i][jc][2] + bb.z;
        v[3] = acc[i][jc][3] + bb.w;
        long idx = base + r * CCH + c0;
        if (RELU) {
#pragma unroll
          for (int q = 0; q < 4; q++) v[q] = fmaxf(v[q], 0.f);
        }
        if (BLEND) {
          s4v ov = *(const s4v*)(oldx + idx);
#pragma unroll
          for (int q = 0; q < 4; q++) v[q] = g * v[q] + gi * bs2f(ov[q]);
        }
        if (OUT_BF16) {
          s4v o;
#pragma unroll
          for (int q = 0; q < 4; q++) o[q] = f2bs(v[q]);
          *(s4v*)((bf16*)dstv + idx) = o;
        } else {
          float4 o = make_float4(v[0], v[1], v[2], v[3]);
          *(float4*)((float*)dstv + idx) = o;
        }
      }
    }
  }
}

// ---------------- penta GEMM (stmt): Q + KV0 + KV1, X read once -------------
// 16 rows/wave; transposed MFMA; KV interleave {K[c],K[c+1],V[c],V[c+1]} at
// slot 2c means regs 0..3 of K+V pack into ONE 16B short8 store per jc.
__global__ __launch_bounds__(256, 2) void gemm_qkv5(
    const bf16* __restrict__ Ab,
    const bf16* __restrict__ WtQ, const float* __restrict__ bQ,
    const bf16* __restrict__ WtK0, const float* __restrict__ bK0,
    const bf16* __restrict__ WtV0, const float* __restrict__ bV0,
    const bf16* __restrict__ WtK1, const float* __restrict__ bK1,
    const bf16* __restrict__ WtV1, const float* __restrict__ bV1,
    bf16* __restrict__ Q, bf16* __restrict__ KV0, bf16* __restrict__ KV1,
    int N)
{
  const int wave = threadIdx.x >> 6, lane = threadIdx.x & 63;
  const int lane15 = lane & 15, quad = lane >> 4;
  const long row0 = (long)blockIdx.x * 64 + wave * 16;

  floatx4 aQ[8], aK0[8], aV0[8], aK1[8], aV1[8];
#pragma unroll
  for (int jc = 0; jc < 8; jc++) {
    aQ[jc] = (floatx4)(0.f); aK0[jc] = (floatx4)(0.f); aV0[jc] = (floatx4)(0.f);
    aK1[jc] = (floatx4)(0.f); aV1[jc] = (floatx4)(0.f);
  }
#pragma unroll
  for (int kq = 0; kq < 4; kq++) {
    const int k0 = kq * 32 + quad * 8;
    long r = row0 + lane15;
    if (r >= N) r = N - 1;
    short8 a = *(const short8*)(Ab + r * CCH + k0);
#pragma unroll
    for (int jc = 0; jc < 8; jc++) {
      const int wrow = (jc * 16 + lane15) * CCH + k0;
      aQ[jc]  = __builtin_amdgcn_mfma_f32_16x16x32_bf16(*(const short8*)(WtQ  + wrow), a, aQ[jc], 0, 0, 0);
      aK0[jc] = __builtin_amdgcn_mfma_f32_16x16x32_bf16(*(const short8*)(WtK0 + wrow), a, aK0[jc], 0, 0, 0);
      aV0[jc] = __builtin_amdgcn_mfma_f32_16x16x32_bf16(*(const short8*)(WtV0 + wrow), a, aV0[jc], 0, 0, 0);
      aK1[jc] = __builtin_amdgcn_mfma_f32_16x16x32_bf16(*(const short8*)(WtK1 + wrow), a, aK1[jc], 0, 0, 0);
      aV1[jc] = __builtin_amdgcn_mfma_f32_16x16x32_bf16(*(const short8*)(WtV1 + wrow), a, aV1[jc], 0, 0, 0);
    }
  }
  long r = row0 + lane15;
  if (r < N) {
#pragma unroll
    for (int jc = 0; jc < 8; jc++) {
      int c0 = jc * 16 + quad * 4;
      float4 bq = *(const float4*)(bQ + c0);
      s4v qo;
      qo[0] = f2bs(aQ[jc][0] + bq.x);
      qo[1] = f2bs(aQ[jc][1] + bq.y);
      qo[2] = f2bs(aQ[jc][2] + bq.z);
      qo[3] = f2bs(aQ[jc][3] + bq.w);
      *(s4v*)(Q + r * CCH + c0) = qo;

      float4 bk = *(const float4*)(bK0 + c0);
      float4 bv = *(const float4*)(bV0 + c0);
      short8 kv;
      kv[0] = f2bs(aK0[jc][0] + bk.x);
      kv[1] = f2bs(aK0[jc][1] + bk.y);
      kv[2] = f2bs(aV0[jc][0] + bv.x);
      kv[3] = f2bs(aV0[jc][1] + bv.y);
      kv[4] = f2bs(aK0[jc][2] + bk.z);
      kv[5] = f2bs(aK0[jc][3] + bk.w);
      kv[6] = f2bs(aV0[jc][2] + bv.z);
      kv[7] = f2bs(aV0[jc][3] + bv.w);
      *(short8*)(KV0 + r * 256 + 2 * c0) = kv;

      bk = *(const float4*)(bK1 + c0);
      bv = *(const float4*)(bV1 + c0);
      kv[0] = f2bs(aK1[jc][0] + bk.x);
      kv[1] = f2bs(aK1[jc][1] + bk.y);
      kv[2] = f2bs(aV1[jc][0] + bv.x);
      kv[3] = f2bs(aV1[jc][1] + bv.y);
      kv[4] = f2bs(aK1[jc][2] + bk.z);
      kv[5] = f2bs(aK1[jc][3] + bk.w);
      kv[6] = f2bs(aV1[jc][2] + bv.z);
      kv[7] = f2bs(aV1[jc][3] + bv.w);
      *(short8*)(KV1 + r * 256 + 2 * c0) = kv;
    }
  }
}

// ---------------- triple GEMM (func): Q + KV2 -------------------------------
__global__ __launch_bounds__(256) void gemm_qkv3(
    const bf16* __restrict__ Ab,
    const bf16* __restrict__ WtQ, const float* __restrict__ bQ,
    const bf16* __restrict__ WtK, const float* __restrict__ bK,
    const bf16* __restrict__ WtV, const float* __restrict__ bV,
    bf16* __restrict__ Q, bf16* __restrict__ KV, int N)
{
  const int wave = threadIdx.x >> 6, lane = threadIdx.x & 63;
  const int lane15 = lane & 15, quad = lane >> 4;
  const long row0 = (long)blockIdx.x * 64 + wave * 16;

  floatx4 aQ[8], aK[8], aV[8];
#pragma unroll
  for (int jc = 0; jc < 8; jc++) {
    aQ[jc] = (floatx4)(0.f); aK[jc] = (floatx4)(0.f); aV[jc] = (floatx4)(0.f);
  }
#pragma unroll
  for (int kq = 0; kq < 4; kq++) {
    const int k0 = kq * 32 + quad * 8;
    long r = row0 + lane15;
    if (r >= N) r = N - 1;
    short8 a = *(const short8*)(Ab + r * CCH + k0);
#pragma unroll
    for (int jc = 0; jc < 8; jc++) {
      const int wrow = (jc * 16 + lane15) * CCH + k0;
      aQ[jc] = __builtin_amdgcn_mfma_f32_16x16x32_bf16(*(const short8*)(WtQ + wrow), a, aQ[jc], 0, 0, 0);
      aK[jc] = __builtin_amdgcn_mfma_f32_16x16x32_bf16(*(const short8*)(WtK + wrow), a, aK[jc], 0, 0, 0);
      aV[jc] = __builtin_amdgcn_mfma_f32_16x16x32_bf16(*(const short8*)(WtV + wrow), a, aV[jc], 0, 0, 0);
    }
  }
  long r = row0 + lane15;
  if (r < N) {
#pragma unroll
    for (int jc = 0; jc < 8; jc++) {
      int c0 = jc * 16 + quad * 4;
      float4 bq = *(const float4*)(bQ + c0);
      s4v qo;
      qo[0] = f2bs(aQ[jc][0] + bq.x);
      qo[1] = f2bs(aQ[jc][1] + bq.y);
      qo[2] = f2bs(aQ[jc][2] + bq.z);
      qo[3] = f2bs(aQ[jc][3] + bq.w);
      *(s4v*)(Q + r * CCH + c0) = qo;

      float4 bk = *(const float4*)(bK + c0);
      float4 bv = *(const float4*)(bV + c0);
      short8 kv;
      kv[0] = f2bs(aK[jc][0] + bk.x);
      kv[1] = f2bs(aK[jc][1] + bk.y);
      kv[2] = f2bs(aV[jc][0] + bv.x);
      kv[3] = f2bs(aV[jc][1] + bv.y);
      kv[4] = f2bs(aK[jc][2] + bk.z);
      kv[5] = f2bs(aK[jc][3] + bk.w);
      kv[6] = f2bs(aV[jc][2] + bv.z);
      kv[7] = f2bs(aV[jc][3] + bv.w);
      *(short8*)(KV + r * 256 + 2 * c0) = kv;
    }
  }
}

// ---------------- CSR build (srcs stored directly) --------------------------
__global__ __launch_bounds__(256) void csr_count(
    const int* __restrict__ dst, int* __restrict__ deg, int* __restrict__ pos)
{
  int e = blockIdx.x * 256 + threadIdx.x;
  if (e < EDGES) pos[e] = atomicAdd(&deg[dst[e]], 1);
}
__global__ __launch_bounds__(256) void csr_alloc(
    const int* __restrict__ deg, int* __restrict__ rowstart,
    int* __restrict__ total, int Ndst)
{
  int n = blockIdx.x * 256 + threadIdx.x;
  if (n < Ndst) rowstart[n] = atomicAdd(total, deg[n]);
}
__global__ __launch_bounds__(256) void csr_fill(
    const int* __restrict__ dst, const int* __restrict__ src,
    const int* __restrict__ rowstart, const int* __restrict__ pos,
    int* __restrict__ srcs)
{
  int e = blockIdx.x * 256 + threadIdx.x;
  if (e < EDGES) srcs[rowstart[dst[e]] + pos[e]] = src[e];
}

// -------- per-relation message (device helper, interleaved KV) --------------
__device__ __forceinline__ float2 relmsg(
    int rs, int g, const int* __restrict__ srcs,
    const bf16* __restrict__ KV, float p, float qx, float qy, int l)
{
  float ax = 0.f, ay = 0.f, den = 0.f;
  for (int j0 = 0; j0 < g; j0 += 64) {
    int cnt = g - j0; if (cnt > 64) cnt = 64;
    int sl = srcs[rs + j0 + (l < cnt ? l : cnt - 1)];
    for (int j = 0; j < cnt; j++) {
      int s = __shfl(sl, j);
      union { uint2 u; bf16 hh[4]; } kv;
      kv.u = *(const uint2*)(KV + (long)s * 256 + 4 * l);
      float prod = qx * b2f(kv.hh[0]) + qy * b2f(kv.hh[1]);
      prod += __shfl_xor(prod, 1);
      prod += __shfl_xor(prod, 2);
      prod += __shfl_xor(prod, 4);
      float ev = __expf(prod * p);
      den += ev;
      ax += ev * b2f(kv.hh[2]);
      ay += ev * b2f(kv.hh[3]);
    }
  }
  float inv = 1.f / (den + 1e-16f);
  return make_float2(ax * inv, ay * inv);
}

// -------- fused aggregation over ALL nodes (one wave per dst node) ----------
__global__ __launch_bounds__(256) void agg_all(
    const int* __restrict__ rs0, const int* __restrict__ dg0, const int* __restrict__ srcs0,
    const int* __restrict__ rs1, const int* __restrict__ dg1, const int* __restrict__ srcs1,
    const int* __restrict__ rs2, const int* __restrict__ dg2, const int* __restrict__ srcs2,
    const bf16* __restrict__ KV0, const bf16* __restrict__ KV1,
    const bf16* __restrict__ KV2, const float* __restrict__ pl,
    const bf16* __restrict__ Qb, bf16* __restrict__ AGGb)
{
  int n = blockIdx.x * 4 + (threadIdx.x >> 6);
  if (n >= N_TOT) return;
  int l = threadIdx.x & 63, h = l >> 3;
  union { uint u; bf16 hh[2]; } qv;
  qv.u = *(const uint*)(Qb + (long)n * CCH + 2 * l);
  float qx = b2f(qv.hh[0]), qy = b2f(qv.hh[1]);
  float rx, ry;
  if (n < N_STMT) {
    float2 m0 = relmsg(rs0[n], dg0[n], srcs0, KV0, pl[h] * 0.25f, qx, qy, l);
    float2 m2 = relmsg(rs2[n], dg2[n], srcs2, KV2, pl[16 + h] * 0.25f, qx, qy, l);
    rx = m0.x + m2.x; ry = m0.y + m2.y;
  } else {
    int nf = n - N_STMT;
    float2 m1 = relmsg(rs1[nf], dg1[nf], srcs1, KV1, pl[8 + h] * 0.25f, qx, qy, l);
    rx = m1.x; ry = m1.y;
  }
  union { uint u; bf16 hh[2]; } o;
  o.hh[0] = __float2bfloat16(rx);
  o.hh[1] = __float2bfloat16(ry);
  *(uint*)(AGGb + (long)n * CCH + 2 * l) = o.u;
}

__global__ __launch_bounds__(256) void zero_out_k(float* __restrict__ out)
{
  long i = ((long)blockIdx.x * 256 + threadIdx.x) * 4;
  *(float4*)(out + i) = make_float4(0.f, 0.f, 0.f, 0.f);
}

extern "C" void kernel_launch(void* const* d_in, const int* in_sizes, int n_in,
                              void* d_out, int out_size, void* d_ws, size_t ws_size,
                              hipStream_t stream)
{
  const int* tok_s = (const int*)d_in[0];
  const int* tok_f = (const int*)d_in[1];
  const int* esrc[3] = {(const int*)d_in[2], (const int*)d_in[4], (const int*)d_in[6]};
  const int* edst[3] = {(const int*)d_in[3], (const int*)d_in[5], (const int*)d_in[7]};
  const float* emb   = (const float*)d_in[8];
  const float* lin_w = (const float*)d_in[9];
  const float* lin_b = (const float*)d_in[10];
  const float* kw = (const float*)d_in[11];
  const float* kb = (const float*)d_in[12];
  const float* qw = (const float*)d_in[13];
  const float* qb = (const float*)d_in[14];
  const float* vw = (const float*)d_in[15];
  const float* vb = (const float*)d_in[16];
  const float* aw = (const float*)d_in[17];
  const float* ab = (const float*)d_in[18];
  const float* skip  = (const float*)d_in[19];
  const float* a_rel = (const float*)d_in[20];
  const float* m_rel = (const float*)d_in[21];
  const float* p_rel = (const float*)d_in[22];

  // ---- ws layout. Total 210,727,056 B. ----
  float* Bf   = (float*)d_ws;           // 12 x 128 fused biases
  bf16*  Xb   = (bf16*)(Bf + 1536);     // 19,200,000  residual stream
  bf16*  AGGb = Xb  + 19200000L;        // 19,200,000  (alias: pooled E)
  bf16*  KV0  = AGGb + 19200000L;       // 25,600,000  stmt r0 KV interleaved
  bf16*  KV1  = KV0 + 25600000L;        // 25,600,000  stmt r1 KV
  bf16*  KV2  = KV1 + 25600000L;        // 12,800,000  func r2 KV
  bf16*  WT   = KV2 + 12800000L;        //    163,840  10 transposed raw mats
  bf16*  WRT  = WT  + 163840L;          //    196,608  12 fused rel mats
  int*   ip   = (int*)(WRT + 196608L);
  int* deg[3]      = {ip, ip + 100000, ip + 150000};
  int* total       = ip + 250000;                      // 4 counters (3 used)
  int* rowstart[3] = {ip + 250004, ip + 350004, ip + 400004};
  int* srcs[3]     = {ip + 500004, ip + 700004, ip + 900004};
  int* pos         = ip + 1100004;                     // 200,000 (shared)
  bf16* EBF   = KV0;                    // 6,400,000 alias: bf16 emb table,
                                        // dead before KV0 is first written
  bf16*  Qb   = (bf16*)d_out;          // bf16 Q scratch in fp32 d_out,
  float* OUTF = (float*)d_out;         // consumed before epilogue overwrites

  const size_t NEED = (size_t)1536 * 4 + (size_t)102760448 * 2
                    + (size_t)1300004 * 4;
  if (ws_size < NEED) {            // soft-fail diagnostic: absmax == |ref|max
    zero_out_k<<<19200000 / 4 / 256, 256, 0, stream>>>(OUTF);
    return;
  }

  const int  Ntype[2] = {N_STMT, N_FUNC};
  const int  edt[3] = {0, 1, 0};
  const int  EB = (EDGES + 255) / 256;

  // ---- CSR build (per relation), reused by both layers ----
  hipMemsetAsync(ip, 0, (size_t)250004 * 4, stream);
  for (int r = 0; r < 3; r++) {
    int Nd = Ntype[edt[r]];
    csr_count<<<EB, 256, 0, stream>>>(edst[r], deg[r], pos);
    csr_alloc<<<(Nd + 255) / 256, 256, 0, stream>>>(deg[r], rowstart[r], total + r, Nd);
    csr_fill<<<EB, 256, 0, stream>>>(edst[r], esrc[r], rowstart[r], pos, srcs[r]);
  }

  // ---- one-time prep ----
  emb2bf<<<3125, 256, 0, stream>>>(emb, EBF);
  transp_w<<<dim3(64, 10), 256, 0, stream>>>(lin_w, qw, aw, WT);
  make_wr_all<<<dim3(64, 12), 256, 0, stream>>>(kw, kb, vw, vb, a_rel, m_rel, WRT, Bf);

  // ---- prologue: pooled embeddings -> fused per-type linear+relu -> Xb ----
  pool_embed<<<N_TOT / 4, 256, 0, stream>>>(tok_s, tok_f, EBF, AGGb);
  gemm_2t<false, true, false, true><<<NBS1 + NBF1, 256, 0, stream>>>(
      AGGb, WT, WT + 16384, lin_b, lin_b + 128, nullptr, Xb, nullptr);

  for (int l = 0; l < 2; l++) {
    int z0 = l * 3 + 0, z1 = l * 3 + 1, z2 = l * 3 + 2;
    // stmt: Q + KV(r0) + KV(r1), X read once
    gemm_qkv5<<<(N_STMT + 63) / 64, 256, 0, stream>>>(
        Xb,
        WT + (2 + l * 2) * 16384, qb + (l * 2) * 128,
        WRT + z0 * 16384, Bf + z0 * 128, WRT + (6 + z0) * 16384, Bf + (6 + z0) * 128,
        WRT + z1 * 16384, Bf + z1 * 128, WRT + (6 + z1) * 16384, Bf + (6 + z1) * 128,
        Qb, KV0, KV1, N_STMT);
    // func: Q + KV(r2)
    gemm_qkv3<<<(N_FUNC + 63) / 64, 256, 0, stream>>>(
        Xb + (long)N_STMT * CCH,
        WT + (2 + l * 2 + 1) * 16384, qb + (l * 2 + 1) * 128,
        WRT + z2 * 16384, Bf + z2 * 128, WRT + (6 + z2) * 16384, Bf + (6 + z2) * 128,
        Qb + (long)N_STMT * CCH, KV2, N_FUNC);
    // fused aggregation over all nodes
    agg_all<<<(N_TOT + 3) / 4, 256, 0, stream>>>(
        rowstart[0], deg[0], srcs[0], rowstart[1], deg[1], srcs[1],
        rowstart[2], deg[2], srcs[2], KV0, KV1, KV2,
        p_rel + l * 24, Qb, AGGb);
    // fused out-proj + gated skip blend. l=0 -> Xb; l=1 -> fp32 d_out.
    if (l == 0)
      gemm_2t<true, false, true, true><<<NBS1 + NBF1, 256, 0, stream>>>(
          AGGb, WT + 6 * 16384, WT + 7 * 16384, ab, ab + 128,
          Xb, Xb, skip);
    else
      gemm_2t<true, false, true, false><<<NBS1 + NBF1, 256, 0, stream>>>(
          AGGb, WT + 8 * 16384, WT + 9 * 16384, ab + 256, ab + 384,
          Xb, OUTF, skip + 2);
  }
}

// Round 4
// 840.805 us; speedup vs baseline: 1.3631x; 1.3631x over previous
//
#include <hip/hip_runtime.h>
#include <hip/hip_bf16.h>

// HGT forward, MI355X. Round 10 (resubmit; R10 bench was an infra failure).
// R9b post-mortem: wide stores didn't help (182->189us); qkv5 still MfmaUtil
// 3.4%, occ 19%. Real bottleneck: 160 L2-latency weight loads per wave feeding
// 160 MFMAs at ~1.5 waves/SIMD (288 regs) -> ~113 cy/load pure latency.
// Fix: block owns 208-row strip; 4 waves split jc 4-way (wave w: jc=2w,2w+1).
// Wave preloads its weights ONCE (5 mats x 2 jc x 4 kq x short8 = 160 VGPR);
// row loop = 4 A-loads + 40 MFMA + 5 stores, zero weight loads. Bias folded
// into acc init. A-tile L1-hot across the 4 waves. Adjacent jc-pair => each
// wave's KV stores cover full 128B lines per row (hedges R9b's write RMW
// inflation 238MB). gemm_2t / agg_all unchanged this round.

typedef __hip_bfloat16 bf16;
typedef __attribute__((ext_vector_type(8))) short short8;
typedef __attribute__((ext_vector_type(4))) short s4v;
typedef __attribute__((ext_vector_type(4))) float floatx4;

#define N_STMT 100000
#define N_FUNC 50000
#define N_TOT  150000
#define EDGES  200000
#define CCH 128
#define NBS1 782   // (N_STMT+127)/128
#define NBF1 391   // (N_FUNC+127)/128
#define RPB 208    // rows per block in qkv kernels (13 iters of 16)

__device__ __forceinline__ float b2f(bf16 x){ return __bfloat162float(x); }
__device__ __forceinline__ float bs2f(short s){
  union { short s; bf16 h; } u; u.s = s; return __bfloat162float(u.h);
}
__device__ __forceinline__ short f2bs(float x){
  union { bf16 h; short s; } u; u.h = __float2bfloat16(x); return u.s;
}
__device__ __forceinline__ float gelu_f(float x){
  return 0.5f * x * (1.f + tanhf(0.7978845608028654f * (x + 0.044715f * x * x * x)));
}

// ---------------- emb fp32 -> bf16 table ------------------------------------
__global__ __launch_bounds__(256) void emb2bf(
    const float* __restrict__ emb, bf16* __restrict__ ebf)
{
  long i = ((long)blockIdx.x * 256 + threadIdx.x) * 8;
  float4 f0 = *(const float4*)(emb + i);
  float4 f1 = *(const float4*)(emb + i + 4);
  short8 o;
  o[0]=f2bs(f0.x); o[1]=f2bs(f0.y); o[2]=f2bs(f0.z); o[3]=f2bs(f0.w);
  o[4]=f2bs(f1.x); o[5]=f2bs(f1.y); o[6]=f2bs(f1.z); o[7]=f2bs(f1.w);
  *(short8*)(ebf + i) = o;
}

// ---------------- pooled embedding: one wave per node -----------------------
__global__ __launch_bounds__(256) void pool_embed(
    const int* __restrict__ tok_s, const int* __restrict__ tok_f,
    const bf16* __restrict__ ebf, bf16* __restrict__ E_out)
{
  int n = blockIdx.x * 4 + (threadIdx.x >> 6);
  int lane = threadIdx.x & 63, g = lane >> 4, c16 = lane & 15;
  const int* tok = (n < N_STMT) ? (tok_s + n * 16) : (tok_f + (n - N_STMT) * 16);
  float acc[8] = {0.f,0.f,0.f,0.f,0.f,0.f,0.f,0.f};
#pragma unroll
  for (int j = 0; j < 4; j++) {
    int v = tok[g * 4 + j];
    short8 row = *(const short8*)(ebf + (long)v * CCH + c16 * 8);
#pragma unroll
    for (int q = 0; q < 8; q++) acc[q] += bs2f(row[q]);
  }
#pragma unroll
  for (int q = 0; q < 8; q++) {
    acc[q] += __shfl_xor(acc[q], 16);
    acc[q] += __shfl_xor(acc[q], 32);
  }
  if (g == 0) {
    short8 o;
#pragma unroll
    for (int q = 0; q < 8; q++) o[q] = f2bs(fmaxf(acc[q] * (1.f/16.f), 0.f));
    *(short8*)(E_out + (long)n * CCH + c16 * 8) = o;
  }
}

// ---------------- transpose+cast 10 raw weight matrices ---------------------
__global__ __launch_bounds__(256) void transp_w(
    const float* __restrict__ lin_w, const float* __restrict__ qw,
    const float* __restrict__ aw, bf16* __restrict__ out)
{
  int mat = blockIdx.y;
  const float* src = (mat < 2) ? lin_w + mat * 16384
                   : (mat < 6) ? qw + (mat - 2) * 16384
                               : aw + (mat - 6) * 16384;
  bf16* dst = out + mat * 16384;
  int idx = blockIdx.x * 256 + threadIdx.x;       // n*128+k
  int n = idx >> 7, k = idx & 127;
  dst[idx] = __float2bfloat16(src[k * 128 + n]);
}

// -------- ALL fused relation weights in one dispatch ------------------------
__global__ __launch_bounds__(256) void make_wr_all(
    const float* __restrict__ kw, const float* __restrict__ kb,
    const float* __restrict__ vw, const float* __restrict__ vb,
    const float* __restrict__ a_rel, const float* __restrict__ m_rel,
    bf16* __restrict__ WRT, float* __restrict__ Bf)
{
  int y = blockIdx.y;
  bool isV = y >= 6;
  int z = isV ? y - 6 : y;
  int l = z / 3, r = z % 3, st = (r == 2) ? 1 : 0;
  const float* W   = (isV ? vw : kw) + (l * 2 + st) * 16384;
  const float* b   = (isV ? vb : kb) + (l * 2 + st) * 128;
  const float* rel = (isV ? m_rel : a_rel) + z * 2048;
  bf16* Wrt = WRT + y * 16384;
  float* br = Bf + y * 128;

  int idx = blockIdx.x * 256 + threadIdx.x;
  if (idx < 128 * 128) {
    int c = idx >> 7, o = idx & 127;
    int h = o >> 4, e = o & 15;
    float acc = 0.f;
#pragma unroll
    for (int d = 0; d < 16; d++)
      acc += W[c * 128 + h * 16 + d] * rel[h * 256 + d * 16 + e];
    Wrt[o * 128 + c] = __float2bfloat16(acc);
  }
  if (idx < 128) {
    int h = idx >> 4, e = idx & 15;
    float acc = 0.f;
#pragma unroll
    for (int d = 0; d < 16; d++)
      acc += b[h * 16 + d] * rel[h * 256 + d * 16 + e];
    br[idx] = acc;
  }
}

// ---------------- fused 2-type MFMA GEMM (lin / out-proj) -------------------
// Grid = NBS1 + NBF1 blocks; block < NBS1 -> stmt rows, else func rows.
// Transposed MFMA: lane15 = node row, (quad*4+reg) = channel -> wide stores.
template <bool GELU_IN, bool RELU, bool BLEND, bool OUT_BF16>
__global__ __launch_bounds__(256) void gemm_2t(
    const bf16* __restrict__ Ab, const bf16* __restrict__ Wt0,
    const bf16* __restrict__ Wt1, const float* __restrict__ bias0,
    const float* __restrict__ bias1, const bf16* __restrict__ oldx,
    void* __restrict__ dstv, const float* __restrict__ skip2)
{
  const int wave = threadIdx.x >> 6, lane = threadIdx.x & 63;
  const int lane15 = lane & 15, quad = lane >> 4;
  const int bid = blockIdx.x;
  const int type = (bid >= NBS1);
  const long base = type ? (long)N_STMT * CCH : 0;
  const int Nrows = type ? N_FUNC : N_STMT;
  const long row0 = (long)(type ? bid - NBS1 : bid) * 128 + wave * 32;
  const bf16* Wt = type ? Wt1 : Wt0;
  const float* bias = type ? bias1 : bias0;

  floatx4 acc[2][8];
#pragma unroll
  for (int i = 0; i < 2; i++)
#pragma unroll
    for (int jc = 0; jc < 8; jc++) acc[i][jc] = (floatx4)(0.f);

#pragma unroll
  for (int kq = 0; kq < 4; kq++) {
    const int k0 = kq * 32 + quad * 8;
    short8 a[2];
#pragma unroll
    for (int i = 0; i < 2; i++) {
      long r = row0 + i * 16 + lane15;
      if (r >= Nrows) r = Nrows - 1;
      short8 t = *(const short8*)(Ab + base + r * CCH + k0);
      if constexpr (GELU_IN) {
#pragma unroll
        for (int q = 0; q < 8; q++) t[q] = f2bs(gelu_f(bs2f(t[q])));
      }
      a[i] = t;
    }
    short8 b[8];
#pragma unroll
    for (int jc = 0; jc < 8; jc++)
      b[jc] = *(const short8*)(Wt + (jc * 16 + lane15) * CCH + k0);
#pragma unroll
    for (int i = 0; i < 2; i++)
#pragma unroll
      for (int jc = 0; jc < 8; jc++)
        acc[i][jc] = __builtin_amdgcn_mfma_f32_16x16x32_bf16(
            b[jc], a[i], acc[i][jc], 0, 0, 0);
  }

  float g = 1.f, gi = 0.f;
  if (BLEND) {
    float sk = skip2[type];
    g = 1.f / (1.f + expf(-sk));
    gi = 1.f - g;
  }
#pragma unroll
  for (int i = 0; i < 2; i++) {
    long r = row0 + i * 16 + lane15;
    if (r < Nrows) {
#pragma unroll
      for (int jc = 0; jc < 8; jc++) {
        int c0 = jc * 16 + quad * 4;
        float4 bb = *(const float4*)(bias + c0);
        float v[4];
        v[0] = acc[i][jc][0] + bb.x;
        v[1] = acc[i][jc][1] + bb.y;
        v[2] = acc[i][jc][2] + bb.z;
        v[3] = acc[i][jc][3] + bb.w;
        long idx = base + r * CCH + c0;
        if (RELU) {
#pragma unroll
          for (int q = 0; q < 4; q++) v[q] = fmaxf(v[q], 0.f);
        }
        if (BLEND) {
          s4v ov = *(const s4v*)(oldx + idx);
#pragma unroll
          for (int q = 0; q < 4; q++) v[q] = g * v[q] + gi * bs2f(ov[q]);
        }
        if (OUT_BF16) {
          s4v o;
#pragma unroll
          for (int q = 0; q < 4; q++) o[q] = f2bs(v[q]);
          *(s4v*)((bf16*)dstv + idx) = o;
        } else {
          float4 o = make_float4(v[0], v[1], v[2], v[3]);
          *(float4*)((float*)dstv + idx) = o;
        }
      }
    }
  }
}

// ------------ QKV GEMM, register-resident weights, jc-split waves -----------
// Block = 256 thr = 4 waves; wave w owns output channels jc in {2w, 2w+1}.
// Block covers rows [bid*RPB, bid*RPB+RPB). Weights preloaded once:
// NM mats x 2 jc x 4 kq x short8 (NM=5: 160 VGPR). Row loop body:
// 4 A-loads + NM*8 MFMA + stores. Bias folded into acc init.
// Mat order NM=5: Q,K0,V0,K1,V1 -> Q, KV0, KV1. NM=3: Q,K,V -> Q, KV0.
template <int NM>
__global__ __launch_bounds__(256, 2) void gemm_qkv_reg(
    const bf16* __restrict__ Ab,
    const bf16* __restrict__ W0, const float* __restrict__ B0,
    const bf16* __restrict__ W1, const float* __restrict__ B1,
    const bf16* __restrict__ W2, const float* __restrict__ B2,
    const bf16* __restrict__ W3, const float* __restrict__ B3,
    const bf16* __restrict__ W4, const float* __restrict__ B4,
    bf16* __restrict__ Q, bf16* __restrict__ KV0, bf16* __restrict__ KV1,
    int N)
{
  const int wave = threadIdx.x >> 6, lane = threadIdx.x & 63;
  const int lane15 = lane & 15, quad = lane >> 4;
  const int jc0 = wave * 2;

  long row = (long)blockIdx.x * RPB;
  if (row >= N) return;
  long rowEnd = row + RPB; if (rowEnd > N) rowEnd = N;

  const bf16* Wm[5]  = {W0, W1, W2, W3, W4};
  const float* Bm[5] = {B0, B1, B2, B3, B4};

  // ---- preload weights (loop-invariant registers) ----
  short8 w[NM][2][4];
#pragma unroll
  for (int m = 0; m < NM; m++)
#pragma unroll
    for (int jj = 0; jj < 2; jj++)
#pragma unroll
      for (int kq = 0; kq < 4; kq++)
        w[m][jj][kq] = *(const short8*)(
            Wm[m] + ((jc0 + jj) * 16 + lane15) * CCH + kq * 32 + quad * 8);

  for (; row < rowEnd; row += 16) {
    long r = row + lane15;
    long rc = (r < N) ? r : (N - 1);
    short8 a[4];
#pragma unroll
    for (int kq = 0; kq < 4; kq++)
      a[kq] = *(const short8*)(Ab + rc * CCH + kq * 32 + quad * 8);

    floatx4 acc[NM][2];
#pragma unroll
    for (int m = 0; m < NM; m++)
#pragma unroll
      for (int jj = 0; jj < 2; jj++) {
        float4 bb = *(const float4*)(Bm[m] + (jc0 + jj) * 16 + quad * 4);
        acc[m][jj][0] = bb.x; acc[m][jj][1] = bb.y;
        acc[m][jj][2] = bb.z; acc[m][jj][3] = bb.w;
      }

#pragma unroll
    for (int kq = 0; kq < 4; kq++)
#pragma unroll
      for (int m = 0; m < NM; m++)
#pragma unroll
        for (int jj = 0; jj < 2; jj++)
          acc[m][jj] = __builtin_amdgcn_mfma_f32_16x16x32_bf16(
              w[m][jj][kq], a[kq], acc[m][jj], 0, 0, 0);

    if (r < N) {
#pragma unroll
      for (int jj = 0; jj < 2; jj++) {
        int c0 = (jc0 + jj) * 16 + quad * 4;
        s4v qo;
        qo[0] = f2bs(acc[0][jj][0]);
        qo[1] = f2bs(acc[0][jj][1]);
        qo[2] = f2bs(acc[0][jj][2]);
        qo[3] = f2bs(acc[0][jj][3]);
        *(s4v*)(Q + r * CCH + c0) = qo;

        short8 kv;
        kv[0] = f2bs(acc[1][jj][0]);
        kv[1] = f2bs(acc[1][jj][1]);
        kv[2] = f2bs(acc[2][jj][0]);
        kv[3] = f2bs(acc[2][jj][1]);
        kv[4] = f2bs(acc[1][jj][2]);
        kv[5] = f2bs(acc[1][jj][3]);
        kv[6] = f2bs(acc[2][jj][2]);
        kv[7] = f2bs(acc[2][jj][3]);
        *(short8*)(KV0 + r * 256 + 2 * c0) = kv;

        if constexpr (NM == 5) {
          kv[0] = f2bs(acc[3][jj][0]);
          kv[1] = f2bs(acc[3][jj][1]);
          kv[2] = f2bs(acc[4][jj][0]);
          kv[3] = f2bs(acc[4][jj][1]);
          kv[4] = f2bs(acc[3][jj][2]);
          kv[5] = f2bs(acc[3][jj][3]);
          kv[6] = f2bs(acc[4][jj][2]);
          kv[7] = f2bs(acc[4][jj][3]);
          *(short8*)(KV1 + r * 256 + 2 * c0) = kv;
        }
      }
    }
  }
}

// ---------------- CSR build (srcs stored directly) --------------------------
__global__ __launch_bounds__(256) void csr_count(
    const int* __restrict__ dst, int* __restrict__ deg, int* __restrict__ pos)
{
  int e = blockIdx.x * 256 + threadIdx.x;
  if (e < EDGES) pos[e] = atomicAdd(&deg[dst[e]], 1);
}
__global__ __launch_bounds__(256) void csr_alloc(
    const int* __restrict__ deg, int* __restrict__ rowstart,
    int* __restrict__ total, int Ndst)
{
  int n = blockIdx.x * 256 + threadIdx.x;
  if (n < Ndst) rowstart[n] = atomicAdd(total, deg[n]);
}
__global__ __launch_bounds__(256) void csr_fill(
    const int* __restrict__ dst, const int* __restrict__ src,
    const int* __restrict__ rowstart, const int* __restrict__ pos,
    int* __restrict__ srcs)
{
  int e = blockIdx.x * 256 + threadIdx.x;
  if (e < EDGES) srcs[rowstart[dst[e]] + pos[e]] = src[e];
}

// -------- per-relation message (device helper, interleaved KV) --------------
__device__ __forceinline__ float2 relmsg(
    int rs, int g, const int* __restrict__ srcs,
    const bf16* __restrict__ KV, float p, float qx, float qy, int l)
{
  float ax = 0.f, ay = 0.f, den = 0.f;
  for (int j0 = 0; j0 < g; j0 += 64) {
    int cnt = g - j0; if (cnt > 64) cnt = 64;
    int sl = srcs[rs + j0 + (l < cnt ? l : cnt - 1)];
    for (int j = 0; j < cnt; j++) {
      int s = __shfl(sl, j);
      union { uint2 u; bf16 hh[4]; } kv;
      kv.u = *(const uint2*)(KV + (long)s * 256 + 4 * l);
      float prod = qx * b2f(kv.hh[0]) + qy * b2f(kv.hh[1]);
      prod += __shfl_xor(prod, 1);
      prod += __shfl_xor(prod, 2);
      prod += __shfl_xor(prod, 4);
      float ev = __expf(prod * p);
      den += ev;
      ax += ev * b2f(kv.hh[2]);
      ay += ev * b2f(kv.hh[3]);
    }
  }
  float inv = 1.f / (den + 1e-16f);
  return make_float2(ax * inv, ay * inv);
}

// -------- fused aggregation over ALL nodes (one wave per dst node) ----------
__global__ __launch_bounds__(256) void agg_all(
    const int* __restrict__ rs0, const int* __restrict__ dg0, const int* __restrict__ srcs0,
    const int* __restrict__ rs1, const int* __restrict__ dg1, const int* __restrict__ srcs1,
    const int* __restrict__ rs2, const int* __restrict__ dg2, const int* __restrict__ srcs2,
    const bf16* __restrict__ KV0, const bf16* __restrict__ KV1,
    const bf16* __restrict__ KV2, const float* __restrict__ pl,
    const bf16* __restrict__ Qb, bf16* __restrict__ AGGb)
{
  int n = blockIdx.x * 4 + (threadIdx.x >> 6);
  if (n >= N_TOT) return;
  int l = threadIdx.x & 63, h = l >> 3;
  union { uint u; bf16 hh[2]; } qv;
  qv.u = *(const uint*)(Qb + (long)n * CCH + 2 * l);
  float qx = b2f(qv.hh[0]), qy = b2f(qv.hh[1]);
  float rx, ry;
  if (n < N_STMT) {
    float2 m0 = relmsg(rs0[n], dg0[n], srcs0, KV0, pl[h] * 0.25f, qx, qy, l);
    float2 m2 = relmsg(rs2[n], dg2[n], srcs2, KV2, pl[16 + h] * 0.25f, qx, qy, l);
    rx = m0.x + m2.x; ry = m0.y + m2.y;
  } else {
    int nf = n - N_STMT;
    float2 m1 = relmsg(rs1[nf], dg1[nf], srcs1, KV1, pl[8 + h] * 0.25f, qx, qy, l);
    rx = m1.x; ry = m1.y;
  }
  union { uint u; bf16 hh[2]; } o;
  o.hh[0] = __float2bfloat16(rx);
  o.hh[1] = __float2bfloat16(ry);
  *(uint*)(AGGb + (long)n * CCH + 2 * l) = o.u;
}

__global__ __launch_bounds__(256) void zero_out_k(float* __restrict__ out)
{
  long i = ((long)blockIdx.x * 256 + threadIdx.x) * 4;
  *(float4*)(out + i) = make_float4(0.f, 0.f, 0.f, 0.f);
}

extern "C" void kernel_launch(void* const* d_in, const int* in_sizes, int n_in,
                              void* d_out, int out_size, void* d_ws, size_t ws_size,
                              hipStream_t stream)
{
  const int* tok_s = (const int*)d_in[0];
  const int* tok_f = (const int*)d_in[1];
  const int* esrc[3] = {(const int*)d_in[2], (const int*)d_in[4], (const int*)d_in[6]};
  const int* edst[3] = {(const int*)d_in[3], (const int*)d_in[5], (const int*)d_in[7]};
  const float* emb   = (const float*)d_in[8];
  const float* lin_w = (const float*)d_in[9];
  const float* lin_b = (const float*)d_in[10];
  const float* kw = (const float*)d_in[11];
  const float* kb = (const float*)d_in[12];
  const float* qw = (const float*)d_in[13];
  const float* qb = (const float*)d_in[14];
  const float* vw = (const float*)d_in[15];
  const float* vb = (const float*)d_in[16];
  const float* aw = (const float*)d_in[17];
  const float* ab = (const float*)d_in[18];
  const float* skip  = (const float*)d_in[19];
  const float* a_rel = (const float*)d_in[20];
  const float* m_rel = (const float*)d_in[21];
  const float* p_rel = (const float*)d_in[22];

  // ---- ws layout. Total 210,727,056 B. ----
  float* Bf   = (float*)d_ws;           // 12 x 128 fused biases
  bf16*  Xb   = (bf16*)(Bf + 1536);     // 19,200,000  residual stream
  bf16*  AGGb = Xb  + 19200000L;        // 19,200,000  (alias: pooled E)
  bf16*  KV0  = AGGb + 19200000L;       // 25,600,000  stmt r0 KV interleaved
  bf16*  KV1  = KV0 + 25600000L;        // 25,600,000  stmt r1 KV
  bf16*  KV2  = KV1 + 25600000L;        // 12,800,000  func r2 KV
  bf16*  WT   = KV2 + 12800000L;        //    163,840  10 transposed raw mats
  bf16*  WRT  = WT  + 163840L;          //    196,608  12 fused rel mats
  int*   ip   = (int*)(WRT + 196608L);
  int* deg[3]      = {ip, ip + 100000, ip + 150000};
  int* total       = ip + 250000;                      // 4 counters (3 used)
  int* rowstart[3] = {ip + 250004, ip + 350004, ip + 400004};
  int* srcs[3]     = {ip + 500004, ip + 700004, ip + 900004};
  int* pos         = ip + 1100004;                     // 200,000 (shared)
  bf16* EBF   = KV0;                    // 6,400,000 alias: bf16 emb table,
                                        // dead before KV0 is first written
  bf16*  Qb   = (bf16*)d_out;          // bf16 Q scratch in fp32 d_out,
  float* OUTF = (float*)d_out;         // consumed before epilogue overwrites

  const size_t NEED = (size_t)1536 * 4 + (size_t)102760448 * 2
                    + (size_t)1300004 * 4;
  if (ws_size < NEED) {            // soft-fail diagnostic: absmax == |ref|max
    zero_out_k<<<19200000 / 4 / 256, 256, 0, stream>>>(OUTF);
    return;
  }

  const int  Ntype[2] = {N_STMT, N_FUNC};
  const int  edt[3] = {0, 1, 0};
  const int  EB = (EDGES + 255) / 256;

  // ---- CSR build (per relation), reused by both layers ----
  hipMemsetAsync(ip, 0, (size_t)250004 * 4, stream);
  for (int r = 0; r < 3; r++) {
    int Nd = Ntype[edt[r]];
    csr_count<<<EB, 256, 0, stream>>>(edst[r], deg[r], pos);
    csr_alloc<<<(Nd + 255) / 256, 256, 0, stream>>>(deg[r], rowstart[r], total + r, Nd);
    csr_fill<<<EB, 256, 0, stream>>>(edst[r], esrc[r], rowstart[r], pos, srcs[r]);
  }

  // ---- one-time prep ----
  emb2bf<<<3125, 256, 0, stream>>>(emb, EBF);
  transp_w<<<dim3(64, 10), 256, 0, stream>>>(lin_w, qw, aw, WT);
  make_wr_all<<<dim3(64, 12), 256, 0, stream>>>(kw, kb, vw, vb, a_rel, m_rel, WRT, Bf);

  // ---- prologue: pooled embeddings -> fused per-type linear+relu -> Xb ----
  pool_embed<<<N_TOT / 4, 256, 0, stream>>>(tok_s, tok_f, EBF, AGGb);
  gemm_2t<false, true, false, true><<<NBS1 + NBF1, 256, 0, stream>>>(
      AGGb, WT, WT + 16384, lin_b, lin_b + 128, nullptr, Xb, nullptr);

  const int GQS = (N_STMT + RPB - 1) / RPB;   // 481
  const int GQF = (N_FUNC + RPB - 1) / RPB;   // 241

  for (int l = 0; l < 2; l++) {
    int z0 = l * 3 + 0, z1 = l * 3 + 1, z2 = l * 3 + 2;
    // stmt: Q + KV(r0) + KV(r1), X read once, weights in registers
    gemm_qkv_reg<5><<<GQS, 256, 0, stream>>>(
        Xb,
        WT + (2 + l * 2) * 16384, qb + (l * 2) * 128,
        WRT + z0 * 16384, Bf + z0 * 128,
        WRT + (6 + z0) * 16384, Bf + (6 + z0) * 128,
        WRT + z1 * 16384, Bf + z1 * 128,
        WRT + (6 + z1) * 16384, Bf + (6 + z1) * 128,
        Qb, KV0, KV1, N_STMT);
    // func: Q + KV(r2)
    gemm_qkv_reg<3><<<GQF, 256, 0, stream>>>(
        Xb + (long)N_STMT * CCH,
        WT + (2 + l * 2 + 1) * 16384, qb + (l * 2 + 1) * 128,
        WRT + z2 * 16384, Bf + z2 * 128,
        WRT + (6 + z2) * 16384, Bf + (6 + z2) * 128,
        nullptr, nullptr, nullptr, nullptr,
        Qb + (long)N_STMT * CCH, KV2, nullptr, N_FUNC);
    // fused aggregation over all nodes
    agg_all<<<(N_TOT + 3) / 4, 256, 0, stream>>>(
        rowstart[0], deg[0], srcs[0], rowstart[1], deg[1], srcs[1],
        rowstart[2], deg[2], srcs[2], KV0, KV1, KV2,
        p_rel + l * 24, Qb, AGGb);
    // fused out-proj + gated skip blend. l=0 -> Xb; l=1 -> fp32 d_out.
    if (l == 0)
      gemm_2t<true, false, true, true><<<NBS1 + NBF1, 256, 0, stream>>>(
          AGGb, WT + 6 * 16384, WT + 7 * 16384, ab, ab + 128,
          Xb, Xb, skip);
    else
      gemm_2t<true, false, true, false><<<NBS1 + NBF1, 256, 0, stream>>>(
          AGGb, WT + 8 * 16384, WT + 9 * 16384, ab + 256, ab + 384,
          Xb, OUTF, skip + 2);
  }
}

// Round 5
// 828.132 us; speedup vs baseline: 1.3840x; 1.0153x over previous
//
#include <hip/hip_runtime.h>
#include <hip/hip_bf16.h>

// HGT forward, MI355X. Round 11: half-wave 2-edge-parallel aggregation.
// R10 profile: agg_all now top (110us x2): VALU 43%, HBM 25%, occ 72%.
// Per-edge cost: 1 readlane + 2x8B load + 4 b2f + 2 fma + 3 DEPENDENT
// shfl_xor (DS chain) + exp + 3 fma, amortized over ~4 edges/node.
// Fix: lane=(p,e); p in [0,32) owns channels 4p..4p+3 (ONE 16B uint4 =
// 2 KV quads), e in {0,1} picks edge 2t+e -> 2 edges/iter, dot-reduce
// spans 4 lanes (2 shfl_xor not 3), cross-half merge + normalize once
// per node per relation. ~13 VALU/edge vs ~20; loads halved in count.
// qkv_reg / gemm_2t / CSR / prep unchanged (R10 verified, 841us).

typedef __hip_bfloat16 bf16;
typedef __attribute__((ext_vector_type(8))) short short8;
typedef __attribute__((ext_vector_type(4))) short s4v;
typedef __attribute__((ext_vector_type(4))) float floatx4;

#define N_STMT 100000
#define N_FUNC 50000
#define N_TOT  150000
#define EDGES  200000
#define CCH 128
#define NBS1 782   // (N_STMT+127)/128
#define NBF1 391   // (N_FUNC+127)/128
#define RPB 208    // rows per block in qkv kernels (13 iters of 16)

__device__ __forceinline__ float b2f(bf16 x){ return __bfloat162float(x); }
__device__ __forceinline__ float bs2f(short s){
  union { short s; bf16 h; } u; u.s = s; return __bfloat162float(u.h);
}
__device__ __forceinline__ short f2bs(float x){
  union { bf16 h; short s; } u; u.h = __float2bfloat16(x); return u.s;
}
__device__ __forceinline__ float gelu_f(float x){
  return 0.5f * x * (1.f + tanhf(0.7978845608028654f * (x + 0.044715f * x * x * x)));
}

// ---------------- emb fp32 -> bf16 table ------------------------------------
__global__ __launch_bounds__(256) void emb2bf(
    const float* __restrict__ emb, bf16* __restrict__ ebf)
{
  long i = ((long)blockIdx.x * 256 + threadIdx.x) * 8;
  float4 f0 = *(const float4*)(emb + i);
  float4 f1 = *(const float4*)(emb + i + 4);
  short8 o;
  o[0]=f2bs(f0.x); o[1]=f2bs(f0.y); o[2]=f2bs(f0.z); o[3]=f2bs(f0.w);
  o[4]=f2bs(f1.x); o[5]=f2bs(f1.y); o[6]=f2bs(f1.z); o[7]=f2bs(f1.w);
  *(short8*)(ebf + i) = o;
}

// ---------------- pooled embedding: one wave per node -----------------------
__global__ __launch_bounds__(256) void pool_embed(
    const int* __restrict__ tok_s, const int* __restrict__ tok_f,
    const bf16* __restrict__ ebf, bf16* __restrict__ E_out)
{
  int n = blockIdx.x * 4 + (threadIdx.x >> 6);
  int lane = threadIdx.x & 63, g = lane >> 4, c16 = lane & 15;
  const int* tok = (n < N_STMT) ? (tok_s + n * 16) : (tok_f + (n - N_STMT) * 16);
  float acc[8] = {0.f,0.f,0.f,0.f,0.f,0.f,0.f,0.f};
#pragma unroll
  for (int j = 0; j < 4; j++) {
    int v = tok[g * 4 + j];
    short8 row = *(const short8*)(ebf + (long)v * CCH + c16 * 8);
#pragma unroll
    for (int q = 0; q < 8; q++) acc[q] += bs2f(row[q]);
  }
#pragma unroll
  for (int q = 0; q < 8; q++) {
    acc[q] += __shfl_xor(acc[q], 16);
    acc[q] += __shfl_xor(acc[q], 32);
  }
  if (g == 0) {
    short8 o;
#pragma unroll
    for (int q = 0; q < 8; q++) o[q] = f2bs(fmaxf(acc[q] * (1.f/16.f), 0.f));
    *(short8*)(E_out + (long)n * CCH + c16 * 8) = o;
  }
}

// ---------------- transpose+cast 10 raw weight matrices ---------------------
__global__ __launch_bounds__(256) void transp_w(
    const float* __restrict__ lin_w, const float* __restrict__ qw,
    const float* __restrict__ aw, bf16* __restrict__ out)
{
  int mat = blockIdx.y;
  const float* src = (mat < 2) ? lin_w + mat * 16384
                   : (mat < 6) ? qw + (mat - 2) * 16384
                               : aw + (mat - 6) * 16384;
  bf16* dst = out + mat * 16384;
  int idx = blockIdx.x * 256 + threadIdx.x;       // n*128+k
  int n = idx >> 7, k = idx & 127;
  dst[idx] = __float2bfloat16(src[k * 128 + n]);
}

// -------- ALL fused relation weights in one dispatch ------------------------
__global__ __launch_bounds__(256) void make_wr_all(
    const float* __restrict__ kw, const float* __restrict__ kb,
    const float* __restrict__ vw, const float* __restrict__ vb,
    const float* __restrict__ a_rel, const float* __restrict__ m_rel,
    bf16* __restrict__ WRT, float* __restrict__ Bf)
{
  int y = blockIdx.y;
  bool isV = y >= 6;
  int z = isV ? y - 6 : y;
  int l = z / 3, r = z % 3, st = (r == 2) ? 1 : 0;
  const float* W   = (isV ? vw : kw) + (l * 2 + st) * 16384;
  const float* b   = (isV ? vb : kb) + (l * 2 + st) * 128;
  const float* rel = (isV ? m_rel : a_rel) + z * 2048;
  bf16* Wrt = WRT + y * 16384;
  float* br = Bf + y * 128;

  int idx = blockIdx.x * 256 + threadIdx.x;
  if (idx < 128 * 128) {
    int c = idx >> 7, o = idx & 127;
    int h = o >> 4, e = o & 15;
    float acc = 0.f;
#pragma unroll
    for (int d = 0; d < 16; d++)
      acc += W[c * 128 + h * 16 + d] * rel[h * 256 + d * 16 + e];
    Wrt[o * 128 + c] = __float2bfloat16(acc);
  }
  if (idx < 128) {
    int h = idx >> 4, e = idx & 15;
    float acc = 0.f;
#pragma unroll
    for (int d = 0; d < 16; d++)
      acc += b[h * 16 + d] * rel[h * 256 + d * 16 + e];
    br[idx] = acc;
  }
}

// ---------------- fused 2-type MFMA GEMM (lin / out-proj) -------------------
template <bool GELU_IN, bool RELU, bool BLEND, bool OUT_BF16>
__global__ __launch_bounds__(256) void gemm_2t(
    const bf16* __restrict__ Ab, const bf16* __restrict__ Wt0,
    const bf16* __restrict__ Wt1, const float* __restrict__ bias0,
    const float* __restrict__ bias1, const bf16* __restrict__ oldx,
    void* __restrict__ dstv, const float* __restrict__ skip2)
{
  const int wave = threadIdx.x >> 6, lane = threadIdx.x & 63;
  const int lane15 = lane & 15, quad = lane >> 4;
  const int bid = blockIdx.x;
  const int type = (bid >= NBS1);
  const long base = type ? (long)N_STMT * CCH : 0;
  const int Nrows = type ? N_FUNC : N_STMT;
  const long row0 = (long)(type ? bid - NBS1 : bid) * 128 + wave * 32;
  const bf16* Wt = type ? Wt1 : Wt0;
  const float* bias = type ? bias1 : bias0;

  floatx4 acc[2][8];
#pragma unroll
  for (int i = 0; i < 2; i++)
#pragma unroll
    for (int jc = 0; jc < 8; jc++) acc[i][jc] = (floatx4)(0.f);

#pragma unroll
  for (int kq = 0; kq < 4; kq++) {
    const int k0 = kq * 32 + quad * 8;
    short8 a[2];
#pragma unroll
    for (int i = 0; i < 2; i++) {
      long r = row0 + i * 16 + lane15;
      if (r >= Nrows) r = Nrows - 1;
      short8 t = *(const short8*)(Ab + base + r * CCH + k0);
      if constexpr (GELU_IN) {
#pragma unroll
        for (int q = 0; q < 8; q++) t[q] = f2bs(gelu_f(bs2f(t[q])));
      }
      a[i] = t;
    }
    short8 b[8];
#pragma unroll
    for (int jc = 0; jc < 8; jc++)
      b[jc] = *(const short8*)(Wt + (jc * 16 + lane15) * CCH + k0);
#pragma unroll
    for (int i = 0; i < 2; i++)
#pragma unroll
      for (int jc = 0; jc < 8; jc++)
        acc[i][jc] = __builtin_amdgcn_mfma_f32_16x16x32_bf16(
            b[jc], a[i], acc[i][jc], 0, 0, 0);
  }

  float g = 1.f, gi = 0.f;
  if (BLEND) {
    float sk = skip2[type];
    g = 1.f / (1.f + expf(-sk));
    gi = 1.f - g;
  }
#pragma unroll
  for (int i = 0; i < 2; i++) {
    long r = row0 + i * 16 + lane15;
    if (r < Nrows) {
#pragma unroll
      for (int jc = 0; jc < 8; jc++) {
        int c0 = jc * 16 + quad * 4;
        float4 bb = *(const float4*)(bias + c0);
        float v[4];
        v[0] = acc[i][jc][0] + bb.x;
        v[1] = acc[i][jc][1] + bb.y;
        v[2] = acc[i][jc][2] + bb.z;
        v[3] = acc[i][jc][3] + bb.w;
        long idx = base + r * CCH + c0;
        if (RELU) {
#pragma unroll
          for (int q = 0; q < 4; q++) v[q] = fmaxf(v[q], 0.f);
        }
        if (BLEND) {
          s4v ov = *(const s4v*)(oldx + idx);
#pragma unroll
          for (int q = 0; q < 4; q++) v[q] = g * v[q] + gi * bs2f(ov[q]);
        }
        if (OUT_BF16) {
          s4v o;
#pragma unroll
          for (int q = 0; q < 4; q++) o[q] = f2bs(v[q]);
          *(s4v*)((bf16*)dstv + idx) = o;
        } else {
          float4 o = make_float4(v[0], v[1], v[2], v[3]);
          *(float4*)((float*)dstv + idx) = o;
        }
      }
    }
  }
}

// ------------ QKV GEMM, register-resident weights, jc-split waves -----------
template <int NM>
__global__ __launch_bounds__(256, 2) void gemm_qkv_reg(
    const bf16* __restrict__ Ab,
    const bf16* __restrict__ W0, const float* __restrict__ B0,
    const bf16* __restrict__ W1, const float* __restrict__ B1,
    const bf16* __restrict__ W2, const float* __restrict__ B2,
    const bf16* __restrict__ W3, const float* __restrict__ B3,
    const bf16* __restrict__ W4, const float* __restrict__ B4,
    bf16* __restrict__ Q, bf16* __restrict__ KV0, bf16* __restrict__ KV1,
    int N)
{
  const int wave = threadIdx.x >> 6, lane = threadIdx.x & 63;
  const int lane15 = lane & 15, quad = lane >> 4;
  const int jc0 = wave * 2;

  long row = (long)blockIdx.x * RPB;
  if (row >= N) return;
  long rowEnd = row + RPB; if (rowEnd > N) rowEnd = N;

  const bf16* Wm[5]  = {W0, W1, W2, W3, W4};
  const float* Bm[5] = {B0, B1, B2, B3, B4};

  short8 w[NM][2][4];
#pragma unroll
  for (int m = 0; m < NM; m++)
#pragma unroll
    for (int jj = 0; jj < 2; jj++)
#pragma unroll
      for (int kq = 0; kq < 4; kq++)
        w[m][jj][kq] = *(const short8*)(
            Wm[m] + ((jc0 + jj) * 16 + lane15) * CCH + kq * 32 + quad * 8);

  for (; row < rowEnd; row += 16) {
    long r = row + lane15;
    long rc = (r < N) ? r : (N - 1);
    short8 a[4];
#pragma unroll
    for (int kq = 0; kq < 4; kq++)
      a[kq] = *(const short8*)(Ab + rc * CCH + kq * 32 + quad * 8);

    floatx4 acc[NM][2];
#pragma unroll
    for (int m = 0; m < NM; m++)
#pragma unroll
      for (int jj = 0; jj < 2; jj++) {
        float4 bb = *(const float4*)(Bm[m] + (jc0 + jj) * 16 + quad * 4);
        acc[m][jj][0] = bb.x; acc[m][jj][1] = bb.y;
        acc[m][jj][2] = bb.z; acc[m][jj][3] = bb.w;
      }

#pragma unroll
    for (int kq = 0; kq < 4; kq++)
#pragma unroll
      for (int m = 0; m < NM; m++)
#pragma unroll
        for (int jj = 0; jj < 2; jj++)
          acc[m][jj] = __builtin_amdgcn_mfma_f32_16x16x32_bf16(
              w[m][jj][kq], a[kq], acc[m][jj], 0, 0, 0);

    if (r < N) {
#pragma unroll
      for (int jj = 0; jj < 2; jj++) {
        int c0 = (jc0 + jj) * 16 + quad * 4;
        s4v qo;
        qo[0] = f2bs(acc[0][jj][0]);
        qo[1] = f2bs(acc[0][jj][1]);
        qo[2] = f2bs(acc[0][jj][2]);
        qo[3] = f2bs(acc[0][jj][3]);
        *(s4v*)(Q + r * CCH + c0) = qo;

        short8 kv;
        kv[0] = f2bs(acc[1][jj][0]);
        kv[1] = f2bs(acc[1][jj][1]);
        kv[2] = f2bs(acc[2][jj][0]);
        kv[3] = f2bs(acc[2][jj][1]);
        kv[4] = f2bs(acc[1][jj][2]);
        kv[5] = f2bs(acc[1][jj][3]);
        kv[6] = f2bs(acc[2][jj][2]);
        kv[7] = f2bs(acc[2][jj][3]);
        *(short8*)(KV0 + r * 256 + 2 * c0) = kv;

        if constexpr (NM == 5) {
          kv[0] = f2bs(acc[3][jj][0]);
          kv[1] = f2bs(acc[3][jj][1]);
          kv[2] = f2bs(acc[4][jj][0]);
          kv[3] = f2bs(acc[4][jj][1]);
          kv[4] = f2bs(acc[3][jj][2]);
          kv[5] = f2bs(acc[3][jj][3]);
          kv[6] = f2bs(acc[4][jj][2]);
          kv[7] = f2bs(acc[4][jj][3]);
          *(short8*)(KV1 + r * 256 + 2 * c0) = kv;
        }
      }
    }
  }
}

// ---------------- CSR build (srcs stored directly) --------------------------
__global__ __launch_bounds__(256) void csr_count(
    const int* __restrict__ dst, int* __restrict__ deg, int* __restrict__ pos)
{
  int e = blockIdx.x * 256 + threadIdx.x;
  if (e < EDGES) pos[e] = atomicAdd(&deg[dst[e]], 1);
}
__global__ __launch_bounds__(256) void csr_alloc(
    const int* __restrict__ deg, int* __restrict__ rowstart,
    int* __restrict__ total, int Ndst)
{
  int n = blockIdx.x * 256 + threadIdx.x;
  if (n < Ndst) rowstart[n] = atomicAdd(total, deg[n]);
}
__global__ __launch_bounds__(256) void csr_fill(
    const int* __restrict__ dst, const int* __restrict__ src,
    const int* __restrict__ rowstart, const int* __restrict__ pos,
    int* __restrict__ srcs)
{
  int e = blockIdx.x * 256 + threadIdx.x;
  if (e < EDGES) srcs[rowstart[dst[e]] + pos[e]] = src[e];
}

// -------- per-relation message: half-wave 2-edge-parallel -------------------
// lane = (p, e): p in [0,32) owns channels 4p..4p+3 (2 interleaved KV quads,
// one 16B load), e in {0,1} handles edge 2t+e. Dot reduce over 4 lanes
// (head h = p>>2). Cross-half merge + normalize once at the end.
__device__ __forceinline__ float4 relmsg2(
    int rs, int g, const int* __restrict__ srcs,
    const bf16* __restrict__ KV, float psc,
    float q0, float q1, float q2, float q3, int p, int e)
{
  float den = 0.f, a0 = 0.f, a1 = 0.f, a2 = 0.f, a3 = 0.f;
  int lane = p + 32 * e;
  for (int j0 = 0; j0 < g; j0 += 64) {
    int cnt = g - j0; if (cnt > 64) cnt = 64;
    int sl = srcs[rs + j0 + (lane < cnt ? lane : cnt - 1)];
    for (int t = 0; t < cnt; t += 2) {
      int s0 = __shfl(sl, t);
      int s1 = __shfl(sl, t + 1 < 64 ? t + 1 : 63);
      int s = e ? s1 : s0;
      union { uint4 u; short sh[8]; } kv;
      kv.u = *(const uint4*)(KV + (long)s * 256 + 8 * p);
      float prod = q0 * bs2f(kv.sh[0]) + q1 * bs2f(kv.sh[1])
                 + q2 * bs2f(kv.sh[4]) + q3 * bs2f(kv.sh[5]);
      prod += __shfl_xor(prod, 1);
      prod += __shfl_xor(prod, 2);
      float ev = __expf(prod * psc);
      if (t + e >= cnt) ev = 0.f;     // mask inactive half on odd tail
      den += ev;
      a0 += ev * bs2f(kv.sh[2]);
      a1 += ev * bs2f(kv.sh[3]);
      a2 += ev * bs2f(kv.sh[6]);
      a3 += ev * bs2f(kv.sh[7]);
    }
  }
  den += __shfl_xor(den, 32);
  a0 += __shfl_xor(a0, 32);
  a1 += __shfl_xor(a1, 32);
  a2 += __shfl_xor(a2, 32);
  a3 += __shfl_xor(a3, 32);
  float inv = 1.f / (den + 1e-16f);
  return make_float4(a0 * inv, a1 * inv, a2 * inv, a3 * inv);
}

// -------- fused aggregation over ALL nodes (one wave per dst node) ----------
__global__ __launch_bounds__(256) void agg_all(
    const int* __restrict__ rs0, const int* __restrict__ dg0, const int* __restrict__ srcs0,
    const int* __restrict__ rs1, const int* __restrict__ dg1, const int* __restrict__ srcs1,
    const int* __restrict__ rs2, const int* __restrict__ dg2, const int* __restrict__ srcs2,
    const bf16* __restrict__ KV0, const bf16* __restrict__ KV1,
    const bf16* __restrict__ KV2, const float* __restrict__ pl,
    const bf16* __restrict__ Qb, bf16* __restrict__ AGGb)
{
  int n = blockIdx.x * 4 + (threadIdx.x >> 6);
  if (n >= N_TOT) return;
  int lane = threadIdx.x & 63;
  int p = lane & 31, e = lane >> 5, h = p >> 2;
  union { uint2 u; short sh[4]; } qv;
  qv.u = *(const uint2*)(Qb + (long)n * CCH + 4 * p);
  float q0 = bs2f(qv.sh[0]), q1 = bs2f(qv.sh[1]);
  float q2 = bs2f(qv.sh[2]), q3 = bs2f(qv.sh[3]);
  float4 m;
  if (n < N_STMT) {
    float4 m0 = relmsg2(rs0[n], dg0[n], srcs0, KV0, pl[h] * 0.25f,
                        q0, q1, q2, q3, p, e);
    float4 m2 = relmsg2(rs2[n], dg2[n], srcs2, KV2, pl[16 + h] * 0.25f,
                        q0, q1, q2, q3, p, e);
    m = make_float4(m0.x + m2.x, m0.y + m2.y, m0.z + m2.z, m0.w + m2.w);
  } else {
    int nf = n - N_STMT;
    m = relmsg2(rs1[nf], dg1[nf], srcs1, KV1, pl[8 + h] * 0.25f,
                q0, q1, q2, q3, p, e);
  }
  if (e == 0) {
    union { uint2 u; short sh[4]; } o;
    o.sh[0] = f2bs(m.x); o.sh[1] = f2bs(m.y);
    o.sh[2] = f2bs(m.z); o.sh[3] = f2bs(m.w);
    *(uint2*)(AGGb + (long)n * CCH + 4 * p) = o.u;
  }
}

__global__ __launch_bounds__(256) void zero_out_k(float* __restrict__ out)
{
  long i = ((long)blockIdx.x * 256 + threadIdx.x) * 4;
  *(float4*)(out + i) = make_float4(0.f, 0.f, 0.f, 0.f);
}

extern "C" void kernel_launch(void* const* d_in, const int* in_sizes, int n_in,
                              void* d_out, int out_size, void* d_ws, size_t ws_size,
                              hipStream_t stream)
{
  const int* tok_s = (const int*)d_in[0];
  const int* tok_f = (const int*)d_in[1];
  const int* esrc[3] = {(const int*)d_in[2], (const int*)d_in[4], (const int*)d_in[6]};
  const int* edst[3] = {(const int*)d_in[3], (const int*)d_in[5], (const int*)d_in[7]};
  const float* emb   = (const float*)d_in[8];
  const float* lin_w = (const float*)d_in[9];
  const float* lin_b = (const float*)d_in[10];
  const float* kw = (const float*)d_in[11];
  const float* kb = (const float*)d_in[12];
  const float* qw = (const float*)d_in[13];
  const float* qb = (const float*)d_in[14];
  const float* vw = (const float*)d_in[15];
  const float* vb = (const float*)d_in[16];
  const float* aw = (const float*)d_in[17];
  const float* ab = (const float*)d_in[18];
  const float* skip  = (const float*)d_in[19];
  const float* a_rel = (const float*)d_in[20];
  const float* m_rel = (const float*)d_in[21];
  const float* p_rel = (const float*)d_in[22];

  // ---- ws layout. Total 210,727,056 B. ----
  float* Bf   = (float*)d_ws;           // 12 x 128 fused biases
  bf16*  Xb   = (bf16*)(Bf + 1536);     // 19,200,000  residual stream
  bf16*  AGGb = Xb  + 19200000L;        // 19,200,000  (alias: pooled E)
  bf16*  KV0  = AGGb + 19200000L;       // 25,600,000  stmt r0 KV interleaved
  bf16*  KV1  = KV0 + 25600000L;        // 25,600,000  stmt r1 KV
  bf16*  KV2  = KV1 + 25600000L;        // 12,800,000  func r2 KV
  bf16*  WT   = KV2 + 12800000L;        //    163,840  10 transposed raw mats
  bf16*  WRT  = WT  + 163840L;          //    196,608  12 fused rel mats
  int*   ip   = (int*)(WRT + 196608L);
  int* deg[3]      = {ip, ip + 100000, ip + 150000};
  int* total       = ip + 250000;                      // 4 counters (3 used)
  int* rowstart[3] = {ip + 250004, ip + 350004, ip + 400004};
  int* srcs[3]     = {ip + 500004, ip + 700004, ip + 900004};
  int* pos         = ip + 1100004;                     // 200,000 (shared)
  bf16* EBF   = KV0;                    // 6,400,000 alias: bf16 emb table,
                                        // dead before KV0 is first written
  bf16*  Qb   = (bf16*)d_out;          // bf16 Q scratch in fp32 d_out,
  float* OUTF = (float*)d_out;         // consumed before epilogue overwrites

  const size_t NEED = (size_t)1536 * 4 + (size_t)102760448 * 2
                    + (size_t)1300004 * 4;
  if (ws_size < NEED) {            // soft-fail diagnostic: absmax == |ref|max
    zero_out_k<<<19200000 / 4 / 256, 256, 0, stream>>>(OUTF);
    return;
  }

  const int  Ntype[2] = {N_STMT, N_FUNC};
  const int  edt[3] = {0, 1, 0};
  const int  EB = (EDGES + 255) / 256;

  // ---- CSR build (per relation), reused by both layers ----
  hipMemsetAsync(ip, 0, (size_t)250004 * 4, stream);
  for (int r = 0; r < 3; r++) {
    int Nd = Ntype[edt[r]];
    csr_count<<<EB, 256, 0, stream>>>(edst[r], deg[r], pos);
    csr_alloc<<<(Nd + 255) / 256, 256, 0, stream>>>(deg[r], rowstart[r], total + r, Nd);
    csr_fill<<<EB, 256, 0, stream>>>(edst[r], esrc[r], rowstart[r], pos, srcs[r]);
  }

  // ---- one-time prep ----
  emb2bf<<<3125, 256, 0, stream>>>(emb, EBF);
  transp_w<<<dim3(64, 10), 256, 0, stream>>>(lin_w, qw, aw, WT);
  make_wr_all<<<dim3(64, 12), 256, 0, stream>>>(kw, kb, vw, vb, a_rel, m_rel, WRT, Bf);

  // ---- prologue: pooled embeddings -> fused per-type linear+relu -> Xb ----
  pool_embed<<<N_TOT / 4, 256, 0, stream>>>(tok_s, tok_f, EBF, AGGb);
  gemm_2t<false, true, false, true><<<NBS1 + NBF1, 256, 0, stream>>>(
      AGGb, WT, WT + 16384, lin_b, lin_b + 128, nullptr, Xb, nullptr);

  const int GQS = (N_STMT + RPB - 1) / RPB;   // 481
  const int GQF = (N_FUNC + RPB - 1) / RPB;   // 241

  for (int l = 0; l < 2; l++) {
    int z0 = l * 3 + 0, z1 = l * 3 + 1, z2 = l * 3 + 2;
    // stmt: Q + KV(r0) + KV(r1), X read once, weights in registers
    gemm_qkv_reg<5><<<GQS, 256, 0, stream>>>(
        Xb,
        WT + (2 + l * 2) * 16384, qb + (l * 2) * 128,
        WRT + z0 * 16384, Bf + z0 * 128,
        WRT + (6 + z0) * 16384, Bf + (6 + z0) * 128,
        WRT + z1 * 16384, Bf + z1 * 128,
        WRT + (6 + z1) * 16384, Bf + (6 + z1) * 128,
        Qb, KV0, KV1, N_STMT);
    // func: Q + KV(r2)
    gemm_qkv_reg<3><<<GQF, 256, 0, stream>>>(
        Xb + (long)N_STMT * CCH,
        WT + (2 + l * 2 + 1) * 16384, qb + (l * 2 + 1) * 128,
        WRT + z2 * 16384, Bf + z2 * 128,
        WRT + (6 + z2) * 16384, Bf + (6 + z2) * 128,
        nullptr, nullptr, nullptr, nullptr,
        Qb + (long)N_STMT * CCH, KV2, nullptr, N_FUNC);
    // fused aggregation over all nodes
    agg_all<<<(N_TOT + 3) / 4, 256, 0, stream>>>(
        rowstart[0], deg[0], srcs[0], rowstart[1], deg[1], srcs[1],
        rowstart[2], deg[2], srcs[2], KV0, KV1, KV2,
        p_rel + l * 24, Qb, AGGb);
    // fused out-proj + gated skip blend. l=0 -> Xb; l=1 -> fp32 d_out.
    if (l == 0)
      gemm_2t<true, false, true, true><<<NBS1 + NBF1, 256, 0, stream>>>(
          AGGb, WT + 6 * 16384, WT + 7 * 16384, ab, ab + 128,
          Xb, Xb, skip);
    else
      gemm_2t<true, false, true, false><<<NBS1 + NBF1, 256, 0, stream>>>(
          AGGb, WT + 8 * 16384, WT + 9 * 16384, ab + 256, ab + 384,
          Xb, OUTF, skip + 2);
  }
}